// Round 6
// baseline (1198.200 us; speedup 1.0000x reference)
//
#include <hip/hip_runtime.h>

#define NN 100000
#define NE 1600000
#define IN_CH 128
#define HID_CH 64
#define OUT_CH 32

#define DB 128                         // dst nodes per block
#define NDB ((NN + DB - 1) / DB)       // 782 dst blocks
#define SRCSH 14                       // src slice = 16384 nodes (2 MB bf16 @64ch)
#define NSB 7                          // 99999>>14 = 6 -> slices 0..6
#define CHUNKH 8192                    // edges/block, histogram pass
#define CHUNKF 16384                   // edges/block, fill pass (run length ~21 words)

typedef unsigned short ushort_t;

__device__ inline ushort_t f2bf(float f) {  // round-to-nearest-even
    union { float f; unsigned u; } v; v.f = f;
    unsigned r = v.u + 0x7fff + ((v.u >> 16) & 1);
    return (ushort_t)(r >> 16);
}
__device__ inline float bf2f(ushort_t h) {
    union { unsigned u; float f; } v; v.u = ((unsigned)h) << 16;
    return v.f;
}

// ---- dst-block histogram ----
__global__ __launch_bounds__(256) void k_bhist(const int* __restrict__ da,
                                               int* __restrict__ bcnt) {
    __shared__ int hist[NDB];
    int t = threadIdx.x;
    for (int i = t; i < NDB; i += 256) hist[i] = 0;
    __syncthreads();
    int base = blockIdx.x * CHUNKH;
    for (int i = 0; i < CHUNKH; i += 256) {
        int e = base + i + t;
        if (e < NE) atomicAdd(&hist[da[e] >> 7], 1);
    }
    __syncthreads();
    for (int i = t; i < NDB; i += 256) {
        int c = hist[i];
        if (c) atomicAdd(&bcnt[i], c);
    }
}

// ---- scan dst-block counts (one block, 1024 threads) ----
__global__ __launch_bounds__(1024) void k_bscan(const int* __restrict__ bcnt,
                                                int* __restrict__ bbase,
                                                int* __restrict__ bcur) {
    __shared__ int lds[1024];
    int t = threadIdx.x;
    int v = (t < NDB) ? bcnt[t] : 0;
    lds[t] = v;
    __syncthreads();
    for (int off = 1; off < 1024; off <<= 1) {
        int x = (t >= off) ? lds[t - off] : 0;
        __syncthreads();
        lds[t] += x;
        __syncthreads();
    }
    int excl = lds[t] - v;
    if (t < NDB) { bbase[t] = excl; bcur[t] = excl; }
    if (t == 0) bbase[NDB] = NE;
}

// ---- fill: bucket by dst-block, packed word = (src<<7)|dlo ----
__global__ __launch_bounds__(256) void k_bfill(const int* __restrict__ sa,
                                               const int* __restrict__ da,
                                               int* __restrict__ bcur,
                                               unsigned* __restrict__ ebuf) {
    __shared__ int hist[NDB];
    __shared__ int lcur[NDB];
    int t = threadIdx.x;
    for (int i = t; i < NDB; i += 256) hist[i] = 0;
    __syncthreads();
    int base = blockIdx.x * CHUNKF;
    for (int i = 0; i < CHUNKF; i += 256) {
        int e = base + i + t;
        if (e < NE) atomicAdd(&hist[da[e] >> 7], 1);
    }
    __syncthreads();
    for (int b = t; b < NDB; b += 256) {
        int c = hist[b];
        lcur[b] = c ? atomicAdd(&bcur[b], c) : 0;
    }
    __syncthreads();
    for (int i = 0; i < CHUNKF; i += 256) {
        int e = base + i + t;
        if (e < NE) {
            int d = da[e];
            int p = atomicAdd(&lcur[d >> 7], 1);
            ebuf[p] = ((unsigned)sa[e] << 7) | (unsigned)(d & 127);
        }
    }
}

// ---- fine: per dst-block, 7-way src-slice partition + degree -> rs ----
__global__ __launch_bounds__(256) void k_bfine2(const unsigned* __restrict__ ebuf,
                                                const int* __restrict__ bbase,
                                                float* __restrict__ rs,
                                                unsigned* __restrict__ ebuf2,
                                                int* __restrict__ cellptr) {
    __shared__ int cnt[DB];
    __shared__ int scnt[8];
    __shared__ int scur[8];
    int b = blockIdx.x, t = threadIdx.x;
    int beg = bbase[b], end = bbase[b + 1];
    if (t < DB) cnt[t] = 0;
    if (t < 8) scnt[t] = 0;
    __syncthreads();
    for (int i = beg + t; i < end; i += 256) {
        unsigned w = ebuf[i];
        atomicAdd(&cnt[w & 127], 1);
        atomicAdd(&scnt[w >> (7 + SRCSH)], 1);
    }
    __syncthreads();
    if (t == 0) {
        int run = beg;
#pragma unroll
        for (int s = 0; s < NSB; ++s) {
            scur[s] = run;
            cellptr[b * 8 + s] = run;
            run += scnt[s];
        }
        cellptr[b * 8 + NSB] = end;
    }
    if (t < DB) {
        int n = b * DB + t;
        if (n < NN) rs[n] = rsqrtf((float)(cnt[t] + 1));
    }
    __syncthreads();
    for (int i = beg + t; i < end; i += 256) {
        unsigned w = ebuf[i];
        int pos = atomicAdd(&scur[w >> (7 + SRCSH)], 1);
        ebuf2[pos] = w;
    }
}

// XOR swizzle for GEMM LDS tiles.
#define SWZ1(n, k) ((n) * 128 + ((k) ^ ((((n) & 7)) << 2)))
#define SWZ2(n, k) ((n) * 64 + ((k) ^ ((((n) & 7)) << 2)))

// ---- tiled GEMM1: xsb[n][c] = bf16(((x[n] @ W1 + b1)[c]) * rs[n]) ----
__global__ __launch_bounds__(256) void k_gemm1(
    const float* __restrict__ x, const float* __restrict__ W1,
    const float* __restrict__ b1, const float* __restrict__ rs,
    ushort_t* __restrict__ xsb) {
    __shared__ float xt[64 * 128];
    __shared__ float w1s[128 * 64];
    int t = threadIdx.x;
    int base = blockIdx.x * 64;

#pragma unroll
    for (int i = 0; i < 8; ++i) {
        int flat = i * 1024 + t * 4;
        int node = flat >> 7, k0 = flat & 127;
        int gn = base + node;
        float4 v = make_float4(0.f, 0.f, 0.f, 0.f);
        if (gn < NN) v = *(const float4*)(x + (size_t)gn * IN_CH + k0);
        *(float4*)&xt[SWZ1(node, k0)] = v;
        *(float4*)&w1s[flat] = *(const float4*)(W1 + flat);
    }
    __syncthreads();

    int tn = t & 15, tc = t >> 4;
    int c0 = tc * 4;
    float acc[4][4];
#pragma unroll
    for (int a = 0; a < 4; ++a)
#pragma unroll
        for (int b = 0; b < 4; ++b) acc[a][b] = 0.f;

    for (int k0 = 0; k0 < 128; k0 += 4) {
        float xq[4][4], wq[4][4];
#pragma unroll
        for (int j = 0; j < 4; ++j)
            *(float4*)&wq[j][0] = *(float4*)&w1s[(k0 + j) * 64 + c0];
#pragma unroll
        for (int jn = 0; jn < 4; ++jn)
            *(float4*)&xq[jn][0] = *(float4*)&xt[SWZ1(tn + jn * 16, k0)];
#pragma unroll
        for (int jn = 0; jn < 4; ++jn)
#pragma unroll
            for (int j = 0; j < 4; ++j)
#pragma unroll
                for (int jc = 0; jc < 4; ++jc)
                    acc[jn][jc] = fmaf(xq[jn][j], wq[j][jc], acc[jn][jc]);
    }

    float4 bb = *(const float4*)&b1[c0];
#pragma unroll
    for (int jn = 0; jn < 4; ++jn) {
        int gn = base + tn + jn * 16;
        if (gn < NN) {
            float r = rs[gn];
            uint2 pk;
            pk.x = (unsigned)f2bf((acc[jn][0] + bb.x) * r) |
                   ((unsigned)f2bf((acc[jn][1] + bb.y) * r) << 16);
            pk.y = (unsigned)f2bf((acc[jn][2] + bb.z) * r) |
                   ((unsigned)f2bf((acc[jn][3] + bb.w) * r) << 16);
            *(uint2*)&xsb[(size_t)gn * HID_CH + c0] = pk;
        }
    }
}

// ---- slice-swept LDS aggregation, layer 1 (+relu+rs) ----
__global__ __launch_bounds__(256) void k_pagg1(
    const unsigned* __restrict__ eb, const int* __restrict__ cellptr,
    const ushort_t* __restrict__ xsb, const float* __restrict__ rs,
    float* __restrict__ h) {
    __shared__ float acc[DB * 64];   // 32 KB
    int b = blockIdx.x, t = threadIdx.x;
    int nbase = b * DB;
    for (int idx = t; idx < DB * 64; idx += 256) {
        int n = nbase + (idx >> 6);
        acc[idx] = (n < NN) ? bf2f(xsb[(size_t)n * 64 + (idx & 63)]) : 0.f;  // self-loop
    }
    __syncthreads();
    int wv = t >> 6, lane = t & 63;
    for (int s = 0; s < NSB; ++s) {
        int cbeg = cellptr[b * 8 + s];
        int cend = cellptr[b * 8 + s + 1];
        int cnt = cend - cbeg;
        int per = (cnt + 3) >> 2;
        int wbeg = cbeg + wv * per;
        int wend = min(wbeg + per, cend);
        int i = wbeg;
        for (; i + 4 <= wend; i += 4) {
            unsigned w0 = eb[i], w1 = eb[i + 1], w2 = eb[i + 2], w3 = eb[i + 3];
            float v0 = bf2f(xsb[(size_t)(w0 >> 7) * 64 + lane]);
            float v1 = bf2f(xsb[(size_t)(w1 >> 7) * 64 + lane]);
            float v2 = bf2f(xsb[(size_t)(w2 >> 7) * 64 + lane]);
            float v3 = bf2f(xsb[(size_t)(w3 >> 7) * 64 + lane]);
            atomicAdd(&acc[(w0 & 127) * 64 + lane], v0);
            atomicAdd(&acc[(w1 & 127) * 64 + lane], v1);
            atomicAdd(&acc[(w2 & 127) * 64 + lane], v2);
            atomicAdd(&acc[(w3 & 127) * 64 + lane], v3);
        }
        for (; i < wend; ++i) {
            unsigned w = eb[i];
            atomicAdd(&acc[(w & 127) * 64 + lane],
                      bf2f(xsb[(size_t)(w >> 7) * 64 + lane]));
        }
        __syncthreads();  // keep waves slice-synchronized (L2 locality)
    }
    for (int idx = t; idx < DB * 64; idx += 256) {
        int n = nbase + (idx >> 6);
        if (n < NN) h[(size_t)n * 64 + (idx & 63)] = fmaxf(acc[idx] * rs[n], 0.f);
    }
}

// ---- tiled GEMM2: ysb[n][c] = bf16(((h[n] @ W2 + b2)[c]) * rs[n]) ----
__global__ __launch_bounds__(256) void k_gemm2(
    const float* __restrict__ h, const float* __restrict__ W2,
    const float* __restrict__ b2, const float* __restrict__ rs,
    ushort_t* __restrict__ ysb) {
    __shared__ float ht[64 * 64];
    __shared__ float w2s[64 * 32];
    int t = threadIdx.x;
    int base = blockIdx.x * 64;

#pragma unroll
    for (int i = 0; i < 4; ++i) {
        int flat = i * 1024 + t * 4;
        int node = flat >> 6, k0 = flat & 63;
        int gn = base + node;
        float4 v = make_float4(0.f, 0.f, 0.f, 0.f);
        if (gn < NN) v = *(const float4*)(h + (size_t)gn * HID_CH + k0);
        *(float4*)&ht[SWZ2(node, k0)] = v;
    }
#pragma unroll
    for (int i = 0; i < 2; ++i) {
        int flat = i * 1024 + t * 4;
        *(float4*)&w2s[flat] = *(const float4*)(W2 + flat);
    }
    __syncthreads();

    int tn = t & 15, tc = t >> 4;
    int c0 = tc * 2;
    float acc[4][2];
#pragma unroll
    for (int a = 0; a < 4; ++a) { acc[a][0] = 0.f; acc[a][1] = 0.f; }

    for (int k0 = 0; k0 < 64; k0 += 4) {
        float xq[4][4], wq[4][2];
#pragma unroll
        for (int j = 0; j < 4; ++j)
            *(float2*)&wq[j][0] = *(float2*)&w2s[(k0 + j) * 32 + c0];
#pragma unroll
        for (int jn = 0; jn < 4; ++jn)
            *(float4*)&xq[jn][0] = *(float4*)&ht[SWZ2(tn + jn * 16, k0)];
#pragma unroll
        for (int jn = 0; jn < 4; ++jn)
#pragma unroll
            for (int j = 0; j < 4; ++j) {
                acc[jn][0] = fmaf(xq[jn][j], wq[j][0], acc[jn][0]);
                acc[jn][1] = fmaf(xq[jn][j], wq[j][1], acc[jn][1]);
            }
    }

    float2 bb = *(const float2*)&b2[c0];
#pragma unroll
    for (int jn = 0; jn < 4; ++jn) {
        int gn = base + tn + jn * 16;
        if (gn < NN) {
            float r = rs[gn];
            unsigned pk = (unsigned)f2bf((acc[jn][0] + bb.x) * r) |
                          ((unsigned)f2bf((acc[jn][1] + bb.y) * r) << 16);
            *(unsigned*)&ysb[(size_t)gn * OUT_CH + c0] = pk;
        }
    }
}

// ---- slice-swept LDS aggregation, layer 2 (+final rs) ----
__global__ __launch_bounds__(256) void k_pagg2(
    const unsigned* __restrict__ eb, const int* __restrict__ cellptr,
    const ushort_t* __restrict__ ysb, const float* __restrict__ rs,
    float* __restrict__ out) {
    __shared__ float acc[DB * 32];   // 16 KB
    int b = blockIdx.x, t = threadIdx.x;
    int nbase = b * DB;
    for (int idx = t; idx < DB * 32; idx += 256) {
        int n = nbase + (idx >> 5);
        acc[idx] = (n < NN) ? bf2f(ysb[(size_t)n * 32 + (idx & 31)]) : 0.f;  // self-loop
    }
    __syncthreads();
    int wv = t >> 6, lane = t & 63;
    int half = lane >> 5, c = lane & 31;
    for (int s = 0; s < NSB; ++s) {
        int cbeg = cellptr[b * 8 + s];
        int cend = cellptr[b * 8 + s + 1];
        int cnt = cend - cbeg;
        int per = (cnt + 3) >> 2;
        int wbeg = cbeg + wv * per;
        int wend = min(wbeg + per, cend);
        int i = wbeg;
        for (; i + 8 <= wend; i += 8) {
#pragma unroll
            for (int u = 0; u < 4; ++u) {
                unsigned w = eb[i + u * 2 + half];
                float v = bf2f(ysb[(size_t)(w >> 7) * 32 + c]);
                atomicAdd(&acc[(w & 127) * 32 + c], v);
            }
        }
        for (; i < wend; i += 2) {
            if (i + half < wend) {
                unsigned w = eb[i + half];
                atomicAdd(&acc[(w & 127) * 32 + c],
                          bf2f(ysb[(size_t)(w >> 7) * 32 + c]));
            }
        }
        __syncthreads();
    }
    for (int idx = t; idx < DB * 32; idx += 256) {
        int n = nbase + (idx >> 5);
        if (n < NN) out[(size_t)n * 32 + (idx & 31)] = acc[idx] * rs[n];
    }
}

extern "C" void kernel_launch(void* const* d_in, const int* in_sizes, int n_in,
                              void* d_out, int out_size, void* d_ws, size_t ws_size,
                              hipStream_t stream) {
    const float* x  = (const float*)d_in[0];
    const int*   ei = (const int*)d_in[1];  // (2, E): row 0 = src, row 1 = dst
    const float* W1 = (const float*)d_in[2];
    const float* b1 = (const float*)d_in[3];
    const float* W2 = (const float*)d_in[4];
    const float* b2 = (const float*)d_in[5];
    const int* sa = ei;
    const int* da = ei + NE;

    char* ws = (char*)d_ws;
    size_t off = 0;
    auto alloc = [&](size_t bytes) {
        void* p = ws + off;
        off += (bytes + 255) & ~(size_t)255;
        return p;
    };
    int*      bcnt    = (int*)alloc((size_t)NDB * 4);
    int*      bbase   = (int*)alloc((size_t)(NDB + 1) * 4);
    int*      bcur    = (int*)alloc((size_t)NDB * 4);
    int*      cellptr = (int*)alloc((size_t)NDB * 8 * 4);
    float*    rs      = (float*)alloc((size_t)NN * 4);
    unsigned* ebuf    = (unsigned*)alloc((size_t)NE * 4);
    unsigned* ebuf2   = (unsigned*)alloc((size_t)NE * 4);
    ushort_t* xsb     = (ushort_t*)alloc((size_t)NN * HID_CH * 2);  // 12.8 MB
    float*    hbuf    = (float*)alloc((size_t)NN * HID_CH * 4);     // 25.6 MB
    ushort_t* ysb     = xsb;  // xsb dead after k_pagg1; reuse
    float*    outp    = (float*)d_out;

    hipMemsetAsync(bcnt, 0, (size_t)NDB * 4, stream);
    const int NBLKH = (NE + CHUNKH - 1) / CHUNKH;  // 196
    const int NBLKF = (NE + CHUNKF - 1) / CHUNKF;  // 98
    k_bhist<<<NBLKH, 256, 0, stream>>>(da, bcnt);
    k_bscan<<<1, 1024, 0, stream>>>(bcnt, bbase, bcur);
    k_bfill<<<NBLKF, 256, 0, stream>>>(sa, da, bcur, ebuf);
    k_bfine2<<<NDB, 256, 0, stream>>>(ebuf, bbase, rs, ebuf2, cellptr);

    const int NBLK_GEMM = (NN + 63) / 64;  // 1563
    k_gemm1<<<NBLK_GEMM, 256, 0, stream>>>(x, W1, b1, rs, xsb);
    k_pagg1<<<NDB, 256, 0, stream>>>(ebuf2, cellptr, xsb, rs, hbuf);
    k_gemm2<<<NBLK_GEMM, 256, 0, stream>>>(hbuf, W2, b2, rs, ysb);
    k_pagg2<<<NDB, 256, 0, stream>>>(ebuf2, cellptr, ysb, rs, outp);
}

// Round 7
// 222.578 us; speedup vs baseline: 5.3833x; 5.3833x over previous
//
#include <hip/hip_runtime.h>

#define NN 100000
#define NE 1600000
#define IN_CH 128
#define HID_CH 64
#define OUT_CH 32
#define NBUCK 391            // ceil(NN/256) coarse buckets of 256 nodes
#define CHUNKA 8192          // edges per block in bucket pass

typedef unsigned short ushort_t;

__device__ inline ushort_t f2bf(float f) {  // round-to-nearest-even
    union { float f; unsigned u; } v; v.f = f;
    unsigned r = v.u + 0x7fff + ((v.u >> 16) & 1);
    return (ushort_t)(r >> 16);
}
__device__ inline float blo(unsigned u) {   // low bf16 of a packed pair
    union { unsigned x; float f; } v; v.x = u << 16; return v.f;
}
__device__ inline float bhi(unsigned u) {   // high bf16 of a packed pair
    union { unsigned x; float f; } v; v.x = u & 0xffff0000u; return v.f;
}

// ---- coarse bucket histogram (dst>>8) ----
__global__ __launch_bounds__(256) void k_bhist(const int* __restrict__ da,
                                               int* __restrict__ bcnt) {
    __shared__ int hist[NBUCK];
    int t = threadIdx.x;
    for (int i = t; i < NBUCK; i += 256) hist[i] = 0;
    __syncthreads();
    int base = blockIdx.x * CHUNKA;
    for (int i = 0; i < CHUNKA; i += 256) {
        int e = base + i + t;
        if (e < NE) atomicAdd(&hist[da[e] >> 8], 1);
    }
    __syncthreads();
    for (int i = t; i < NBUCK; i += 256) {
        int c = hist[i];
        if (c) atomicAdd(&bcnt[i], c);
    }
}

// ---- scan bucket counts -> bucket bases & cursors (one block) ----
__global__ __launch_bounds__(512) void k_bscan(const int* __restrict__ bcnt,
                                               int* __restrict__ bbase,
                                               int* __restrict__ bcur,
                                               int* __restrict__ rowptr) {
    __shared__ int lds[512];
    int t = threadIdx.x;
    int v = (t < NBUCK) ? bcnt[t] : 0;
    lds[t] = v;
    __syncthreads();
    for (int off = 1; off < 512; off <<= 1) {
        int x = (t >= off) ? lds[t - off] : 0;
        __syncthreads();
        lds[t] += x;
        __syncthreads();
    }
    int excl = lds[t] - v;
    if (t < NBUCK) { bbase[t] = excl; bcur[t] = excl; }
    if (t == 0) { bbase[NBUCK] = NE; rowptr[NN] = NE; }
}

// ---- bucket fill: per-(block,bucket) contiguous runs, packed (src<<8|dlow) ----
__global__ __launch_bounds__(256) void k_bfill(const int* __restrict__ sa,
                                               const int* __restrict__ da,
                                               int* __restrict__ bcur,
                                               unsigned* __restrict__ ebuf) {
    __shared__ int hist[NBUCK];
    __shared__ int lcur[NBUCK];
    int t = threadIdx.x;
    for (int i = t; i < NBUCK; i += 256) hist[i] = 0;
    __syncthreads();
    int base = blockIdx.x * CHUNKA;
    for (int i = 0; i < CHUNKA; i += 256) {
        int e = base + i + t;
        if (e < NE) atomicAdd(&hist[da[e] >> 8], 1);
    }
    __syncthreads();
    for (int b = t; b < NBUCK; b += 256) {
        int c = hist[b];
        lcur[b] = c ? atomicAdd(&bcur[b], c) : 0;
    }
    __syncthreads();
    for (int i = 0; i < CHUNKA; i += 256) {
        int e = base + i + t;
        if (e < NE) {
            int d = da[e];
            int p = atomicAdd(&lcur[d >> 8], 1);
            ebuf[p] = ((unsigned)sa[e] << 8) | (unsigned)(d & 255);
        }
    }
}

// ---- fine pass: one block per bucket -> rowptr, rs, col ----
__global__ __launch_bounds__(256) void k_bfine(const unsigned* __restrict__ ebuf,
                                               const int* __restrict__ bbase,
                                               int* __restrict__ rowptr,
                                               float* __restrict__ rs,
                                               int* __restrict__ col) {
    __shared__ int cnt[256];
    __shared__ int cur[256];
    __shared__ int scn[256];
    int b = blockIdx.x, t = threadIdx.x;
    int nb = NN - b * 256; if (nb > 256) nb = 256;
    int beg = bbase[b], end = bbase[b + 1];
    cnt[t] = 0;
    __syncthreads();
    for (int i = beg + t; i < end; i += 256) atomicAdd(&cnt[ebuf[i] & 255], 1);
    __syncthreads();
    int v = cnt[t];
    scn[t] = v;
    __syncthreads();
    for (int off = 1; off < 256; off <<= 1) {
        int x = (t >= off) ? scn[t - off] : 0;
        __syncthreads();
        scn[t] += x;
        __syncthreads();
    }
    int excl = scn[t] - v;
    if (t < nb) {
        rowptr[b * 256 + t] = beg + excl;
        rs[b * 256 + t] = rsqrtf((float)(v + 1));
        cur[t] = beg + excl;
    }
    __syncthreads();
    for (int i = beg + t; i < end; i += 256) {
        unsigned p = ebuf[i];
        int pos = atomicAdd(&cur[p & 255], 1);
        col[pos] = (int)(p >> 8);
    }
}

// XOR swizzle for GEMM LDS tiles.
#define SWZ1(n, k) ((n) * 128 + ((k) ^ ((((n) & 7)) << 2)))
#define SWZ2(n, k) ((n) * 64 + ((k) ^ ((((n) & 7)) << 2)))

// ---- tiled GEMM1: xsb[n][c] = bf16(((x[n] @ W1 + b1)[c]) * rs[n]) ----
__global__ __launch_bounds__(256) void k_gemm1(
    const float* __restrict__ x, const float* __restrict__ W1,
    const float* __restrict__ b1, const float* __restrict__ rs,
    ushort_t* __restrict__ xsb) {
    __shared__ float xt[64 * 128];
    __shared__ float w1s[128 * 64];
    int t = threadIdx.x;
    int base = blockIdx.x * 64;

#pragma unroll
    for (int i = 0; i < 8; ++i) {
        int flat = i * 1024 + t * 4;
        int node = flat >> 7, k0 = flat & 127;
        int gn = base + node;
        float4 v = make_float4(0.f, 0.f, 0.f, 0.f);
        if (gn < NN) v = *(const float4*)(x + (size_t)gn * IN_CH + k0);
        *(float4*)&xt[SWZ1(node, k0)] = v;
        *(float4*)&w1s[flat] = *(const float4*)(W1 + flat);
    }
    __syncthreads();

    int tn = t & 15, tc = t >> 4;
    int c0 = tc * 4;
    float acc[4][4];
#pragma unroll
    for (int a = 0; a < 4; ++a)
#pragma unroll
        for (int b = 0; b < 4; ++b) acc[a][b] = 0.f;

    for (int k0 = 0; k0 < 128; k0 += 4) {
        float xq[4][4], wq[4][4];
#pragma unroll
        for (int j = 0; j < 4; ++j)
            *(float4*)&wq[j][0] = *(float4*)&w1s[(k0 + j) * 64 + c0];
#pragma unroll
        for (int jn = 0; jn < 4; ++jn)
            *(float4*)&xq[jn][0] = *(float4*)&xt[SWZ1(tn + jn * 16, k0)];
#pragma unroll
        for (int jn = 0; jn < 4; ++jn)
#pragma unroll
            for (int j = 0; j < 4; ++j)
#pragma unroll
                for (int jc = 0; jc < 4; ++jc)
                    acc[jn][jc] = fmaf(xq[jn][j], wq[j][jc], acc[jn][jc]);
    }

    float4 bb = *(const float4*)&b1[c0];
#pragma unroll
    for (int jn = 0; jn < 4; ++jn) {
        int gn = base + tn + jn * 16;
        if (gn < NN) {
            float r = rs[gn];
            uint2 pk;
            pk.x = (unsigned)f2bf((acc[jn][0] + bb.x) * r) |
                   ((unsigned)f2bf((acc[jn][1] + bb.y) * r) << 16);
            pk.y = (unsigned)f2bf((acc[jn][2] + bb.z) * r) |
                   ((unsigned)f2bf((acc[jn][3] + bb.w) * r) << 16);
            *(uint2*)&xsb[(size_t)gn * HID_CH + c0] = pk;
        }
    }
}

// ---- pull agg layer 1: wave=row, 4 lane-groups x 16 lanes, 4 edges/iter ----
// lane loads uint2 = 4 bf16 channels; group g handles edge i+g.
__global__ __launch_bounds__(256) void k_agg1(
    const int* __restrict__ rowptr, const int* __restrict__ col,
    const ushort_t* __restrict__ xsb, const float* __restrict__ rs,
    float* __restrict__ h) {
    int gid = blockIdx.x * blockDim.x + threadIdx.x;
    int n = gid >> 6;
    if (n >= NN) return;
    int lane = threadIdx.x & 63;
    int g = lane >> 4;          // group 0..3
    unsigned c0 = (unsigned)(lane & 15) * 4;  // channels c0..c0+3
    int beg = rowptr[n], end = rowptr[n + 1];

    float a0 = 0.f, a1 = 0.f, a2 = 0.f, a3 = 0.f;
    if (g == 0) {  // self-loop seeded once
        uint2 sv = *(const uint2*)&xsb[(unsigned)n * 64u + c0];
        a0 = blo(sv.x); a1 = bhi(sv.x); a2 = blo(sv.y); a3 = bhi(sv.y);
    }

    int i = beg;
    for (; i + 8 <= end; i += 8) {  // 8 edges per iter (2 per group)
        int s0 = col[i + g];
        int s1 = col[i + 4 + g];
        uint2 v0 = *(const uint2*)&xsb[(unsigned)s0 * 64u + c0];
        uint2 v1 = *(const uint2*)&xsb[(unsigned)s1 * 64u + c0];
        a0 += blo(v0.x); a1 += bhi(v0.x); a2 += blo(v0.y); a3 += bhi(v0.y);
        a0 += blo(v1.x); a1 += bhi(v1.x); a2 += blo(v1.y); a3 += bhi(v1.y);
    }
    if (i + 4 <= end) {
        int s0 = col[i + g];
        uint2 v0 = *(const uint2*)&xsb[(unsigned)s0 * 64u + c0];
        a0 += blo(v0.x); a1 += bhi(v0.x); a2 += blo(v0.y); a3 += bhi(v0.y);
        i += 4;
    }
    int r = end - i;  // 0..3
    if (g < r) {
        int s0 = col[i + g];
        uint2 v0 = *(const uint2*)&xsb[(unsigned)s0 * 64u + c0];
        a0 += blo(v0.x); a1 += bhi(v0.x); a2 += blo(v0.y); a3 += bhi(v0.y);
    }

    // combine the 4 groups (xor 16, 32)
    a0 += __shfl_xor(a0, 16); a1 += __shfl_xor(a1, 16);
    a2 += __shfl_xor(a2, 16); a3 += __shfl_xor(a3, 16);
    a0 += __shfl_xor(a0, 32); a1 += __shfl_xor(a1, 32);
    a2 += __shfl_xor(a2, 32); a3 += __shfl_xor(a3, 32);

    if (g == 0) {
        float rn = rs[n];
        float4 o;
        o.x = fmaxf(a0 * rn, 0.f);
        o.y = fmaxf(a1 * rn, 0.f);
        o.z = fmaxf(a2 * rn, 0.f);
        o.w = fmaxf(a3 * rn, 0.f);
        *(float4*)&h[(size_t)n * HID_CH + c0] = o;
    }
}

// ---- tiled GEMM2: ysb[n][c] = bf16(((h[n] @ W2 + b2)[c]) * rs[n]) ----
__global__ __launch_bounds__(256) void k_gemm2(
    const float* __restrict__ h, const float* __restrict__ W2,
    const float* __restrict__ b2, const float* __restrict__ rs,
    ushort_t* __restrict__ ysb) {
    __shared__ float ht[64 * 64];
    __shared__ float w2s[64 * 32];
    int t = threadIdx.x;
    int base = blockIdx.x * 64;

#pragma unroll
    for (int i = 0; i < 4; ++i) {
        int flat = i * 1024 + t * 4;
        int node = flat >> 6, k0 = flat & 63;
        int gn = base + node;
        float4 v = make_float4(0.f, 0.f, 0.f, 0.f);
        if (gn < NN) v = *(const float4*)(h + (size_t)gn * HID_CH + k0);
        *(float4*)&ht[SWZ2(node, k0)] = v;
    }
#pragma unroll
    for (int i = 0; i < 2; ++i) {
        int flat = i * 1024 + t * 4;
        *(float4*)&w2s[flat] = *(const float4*)(W2 + flat);
    }
    __syncthreads();

    int tn = t & 15, tc = t >> 4;
    int c0 = tc * 2;
    float acc[4][2];
#pragma unroll
    for (int a = 0; a < 4; ++a) { acc[a][0] = 0.f; acc[a][1] = 0.f; }

    for (int k0 = 0; k0 < 64; k0 += 4) {
        float xq[4][4], wq[4][2];
#pragma unroll
        for (int j = 0; j < 4; ++j)
            *(float2*)&wq[j][0] = *(float2*)&w2s[(k0 + j) * 32 + c0];
#pragma unroll
        for (int jn = 0; jn < 4; ++jn)
            *(float4*)&xq[jn][0] = *(float4*)&ht[SWZ2(tn + jn * 16, k0)];
#pragma unroll
        for (int jn = 0; jn < 4; ++jn)
#pragma unroll
            for (int j = 0; j < 4; ++j) {
                acc[jn][0] = fmaf(xq[jn][j], wq[j][0], acc[jn][0]);
                acc[jn][1] = fmaf(xq[jn][j], wq[j][1], acc[jn][1]);
            }
    }

    float2 bb = *(const float2*)&b2[c0];
#pragma unroll
    for (int jn = 0; jn < 4; ++jn) {
        int gn = base + tn + jn * 16;
        if (gn < NN) {
            float r = rs[gn];
            unsigned pk = (unsigned)f2bf((acc[jn][0] + bb.x) * r) |
                          ((unsigned)f2bf((acc[jn][1] + bb.y) * r) << 16);
            *(unsigned*)&ysb[(size_t)gn * OUT_CH + c0] = pk;
        }
    }
}

// ---- pull agg layer 2: wave=row, 8 lane-groups x 8 lanes, 8 edges/iter ----
__global__ __launch_bounds__(256) void k_agg2(
    const int* __restrict__ rowptr, const int* __restrict__ col,
    const ushort_t* __restrict__ ysb, const float* __restrict__ rs,
    float* __restrict__ out) {
    int gid = blockIdx.x * blockDim.x + threadIdx.x;
    int n = gid >> 6;
    if (n >= NN) return;
    int lane = threadIdx.x & 63;
    int g = lane >> 3;          // group 0..7
    unsigned c0 = (unsigned)(lane & 7) * 4;  // channels c0..c0+3
    int beg = rowptr[n], end = rowptr[n + 1];

    float a0 = 0.f, a1 = 0.f, a2 = 0.f, a3 = 0.f;
    if (g == 0) {
        uint2 sv = *(const uint2*)&ysb[(unsigned)n * 32u + c0];
        a0 = blo(sv.x); a1 = bhi(sv.x); a2 = blo(sv.y); a3 = bhi(sv.y);
    }

    int i = beg;
    for (; i + 16 <= end; i += 16) {  // 16 edges per iter (2 per group)
        int s0 = col[i + g];
        int s1 = col[i + 8 + g];
        uint2 v0 = *(const uint2*)&ysb[(unsigned)s0 * 32u + c0];
        uint2 v1 = *(const uint2*)&ysb[(unsigned)s1 * 32u + c0];
        a0 += blo(v0.x); a1 += bhi(v0.x); a2 += blo(v0.y); a3 += bhi(v0.y);
        a0 += blo(v1.x); a1 += bhi(v1.x); a2 += blo(v1.y); a3 += bhi(v1.y);
    }
    if (i + 8 <= end) {
        int s0 = col[i + g];
        uint2 v0 = *(const uint2*)&ysb[(unsigned)s0 * 32u + c0];
        a0 += blo(v0.x); a1 += bhi(v0.x); a2 += blo(v0.y); a3 += bhi(v0.y);
        i += 8;
    }
    int r = end - i;  // 0..7
    if (g < r) {
        int s0 = col[i + g];
        uint2 v0 = *(const uint2*)&ysb[(unsigned)s0 * 32u + c0];
        a0 += blo(v0.x); a1 += bhi(v0.x); a2 += blo(v0.y); a3 += bhi(v0.y);
    }

    // combine the 8 groups (xor 8, 16, 32)
    a0 += __shfl_xor(a0, 8);  a1 += __shfl_xor(a1, 8);
    a2 += __shfl_xor(a2, 8);  a3 += __shfl_xor(a3, 8);
    a0 += __shfl_xor(a0, 16); a1 += __shfl_xor(a1, 16);
    a2 += __shfl_xor(a2, 16); a3 += __shfl_xor(a3, 16);
    a0 += __shfl_xor(a0, 32); a1 += __shfl_xor(a1, 32);
    a2 += __shfl_xor(a2, 32); a3 += __shfl_xor(a3, 32);

    if (g == 0) {
        float rn = rs[n];
        float4 o;
        o.x = a0 * rn; o.y = a1 * rn; o.z = a2 * rn; o.w = a3 * rn;
        *(float4*)&out[(size_t)n * OUT_CH + c0] = o;
    }
}

extern "C" void kernel_launch(void* const* d_in, const int* in_sizes, int n_in,
                              void* d_out, int out_size, void* d_ws, size_t ws_size,
                              hipStream_t stream) {
    const float* x  = (const float*)d_in[0];
    const int*   ei = (const int*)d_in[1];  // (2, E): row 0 = src, row 1 = dst
    const float* W1 = (const float*)d_in[2];
    const float* b1 = (const float*)d_in[3];
    const float* W2 = (const float*)d_in[4];
    const float* b2 = (const float*)d_in[5];
    const int* sa = ei;
    const int* da = ei + NE;

    char* ws = (char*)d_ws;
    size_t off = 0;
    auto alloc = [&](size_t bytes) {
        void* p = ws + off;
        off += (bytes + 255) & ~(size_t)255;
        return p;
    };
    int*      bcnt   = (int*)alloc((size_t)NBUCK * 4);
    int*      bbase  = (int*)alloc((size_t)(NBUCK + 1) * 4);
    int*      bcur   = (int*)alloc((size_t)NBUCK * 4);
    int*      rowptr = (int*)alloc((size_t)(NN + 1) * 4);
    float*    rs     = (float*)alloc((size_t)NN * 4);
    unsigned* ebuf   = (unsigned*)alloc((size_t)NE * 4);
    int*      col    = (int*)alloc((size_t)NE * 4);
    ushort_t* xsb    = (ushort_t*)alloc((size_t)NN * HID_CH * 2);  // 12.8 MB
    float*    hbuf   = (float*)alloc((size_t)NN * HID_CH * 4);     // 25.6 MB
    ushort_t* ysb    = xsb;  // xsb dead after k_agg1; reuse for ysb
    float*    outp   = (float*)d_out;

    const int B = 256;
    const int NBLKA = (NE + CHUNKA - 1) / CHUNKA;  // 196
    hipMemsetAsync(bcnt, 0, (size_t)NBUCK * 4, stream);
    k_bhist<<<NBLKA, 256, 0, stream>>>(da, bcnt);
    k_bscan<<<1, 512, 0, stream>>>(bcnt, bbase, bcur, rowptr);
    k_bfill<<<NBLKA, 256, 0, stream>>>(sa, da, bcur, ebuf);
    k_bfine<<<NBUCK, 256, 0, stream>>>(ebuf, bbase, rowptr, rs, col);

    const int NBLK_GEMM = (NN + 63) / 64;  // 1563
    k_gemm1<<<NBLK_GEMM, 256, 0, stream>>>(x, W1, b1, rs, xsb);
    k_agg1<<<(NN * 64 + B - 1) / B, B, 0, stream>>>(rowptr, col, xsb, rs, hbuf);
    k_gemm2<<<NBLK_GEMM, 256, 0, stream>>>(hbuf, W2, b2, rs, ysb);
    k_agg2<<<(NN * 64 + B - 1) / B, B, 0, stream>>>(rowptr, col, ysb, rs, outp);
}

// Round 8
// 221.016 us; speedup vs baseline: 5.4213x; 1.0071x over previous
//
#include <hip/hip_runtime.h>

#define NN 100000
#define NE 1600000
#define IN_CH 128
#define HID_CH 64
#define OUT_CH 32
#define NBUCK 391            // ceil(NN/256) coarse buckets of 256 nodes
#define CHUNKA 8192          // edges per block in bucket pass

typedef unsigned short ushort_t;

__device__ inline ushort_t f2bf(float f) {  // round-to-nearest-even
    union { float f; unsigned u; } v; v.f = f;
    unsigned r = v.u + 0x7fff + ((v.u >> 16) & 1);
    return (ushort_t)(r >> 16);
}
__device__ inline float blo(unsigned u) {   // low bf16 of a packed pair
    union { unsigned x; float f; } v; v.x = u << 16; return v.f;
}
__device__ inline float bhi(unsigned u) {   // high bf16 of a packed pair
    union { unsigned x; float f; } v; v.x = u & 0xffff0000u; return v.f;
}

// ---- coarse bucket histogram (dst>>8) ----
__global__ __launch_bounds__(256) void k_bhist(const int* __restrict__ da,
                                               int* __restrict__ bcnt) {
    __shared__ int hist[NBUCK];
    int t = threadIdx.x;
    for (int i = t; i < NBUCK; i += 256) hist[i] = 0;
    __syncthreads();
    int base = blockIdx.x * CHUNKA;
    for (int i = 0; i < CHUNKA; i += 256) {
        int e = base + i + t;
        if (e < NE) atomicAdd(&hist[da[e] >> 8], 1);
    }
    __syncthreads();
    for (int i = t; i < NBUCK; i += 256) {
        int c = hist[i];
        if (c) atomicAdd(&bcnt[i], c);
    }
}

// ---- scan bucket counts -> bucket bases & cursors (one block) ----
__global__ __launch_bounds__(512) void k_bscan(const int* __restrict__ bcnt,
                                               int* __restrict__ bbase,
                                               int* __restrict__ bcur,
                                               int* __restrict__ rowptr) {
    __shared__ int lds[512];
    int t = threadIdx.x;
    int v = (t < NBUCK) ? bcnt[t] : 0;
    lds[t] = v;
    __syncthreads();
    for (int off = 1; off < 512; off <<= 1) {
        int x = (t >= off) ? lds[t - off] : 0;
        __syncthreads();
        lds[t] += x;
        __syncthreads();
    }
    int excl = lds[t] - v;
    if (t < NBUCK) { bbase[t] = excl; bcur[t] = excl; }
    if (t == 0) { bbase[NBUCK] = NE; rowptr[NN] = NE; }
}

// ---- bucket fill: per-(block,bucket) contiguous runs, packed (src<<8|dlow) ----
__global__ __launch_bounds__(256) void k_bfill(const int* __restrict__ sa,
                                               const int* __restrict__ da,
                                               int* __restrict__ bcur,
                                               unsigned* __restrict__ ebuf) {
    __shared__ int hist[NBUCK];
    __shared__ int lcur[NBUCK];
    int t = threadIdx.x;
    for (int i = t; i < NBUCK; i += 256) hist[i] = 0;
    __syncthreads();
    int base = blockIdx.x * CHUNKA;
    for (int i = 0; i < CHUNKA; i += 256) {
        int e = base + i + t;
        if (e < NE) atomicAdd(&hist[da[e] >> 8], 1);
    }
    __syncthreads();
    for (int b = t; b < NBUCK; b += 256) {
        int c = hist[b];
        lcur[b] = c ? atomicAdd(&bcur[b], c) : 0;
    }
    __syncthreads();
    for (int i = 0; i < CHUNKA; i += 256) {
        int e = base + i + t;
        if (e < NE) {
            int d = da[e];
            int p = atomicAdd(&lcur[d >> 8], 1);
            ebuf[p] = ((unsigned)sa[e] << 8) | (unsigned)(d & 255);
        }
    }
}

// ---- fine pass: one block per bucket -> rowptr, rs, col ----
__global__ __launch_bounds__(256) void k_bfine(const unsigned* __restrict__ ebuf,
                                               const int* __restrict__ bbase,
                                               int* __restrict__ rowptr,
                                               float* __restrict__ rs,
                                               int* __restrict__ col) {
    __shared__ int cnt[256];
    __shared__ int cur[256];
    __shared__ int scn[256];
    int b = blockIdx.x, t = threadIdx.x;
    int nb = NN - b * 256; if (nb > 256) nb = 256;
    int beg = bbase[b], end = bbase[b + 1];
    cnt[t] = 0;
    __syncthreads();
    for (int i = beg + t; i < end; i += 256) atomicAdd(&cnt[ebuf[i] & 255], 1);
    __syncthreads();
    int v = cnt[t];
    scn[t] = v;
    __syncthreads();
    for (int off = 1; off < 256; off <<= 1) {
        int x = (t >= off) ? scn[t - off] : 0;
        __syncthreads();
        scn[t] += x;
        __syncthreads();
    }
    int excl = scn[t] - v;
    if (t < nb) {
        rowptr[b * 256 + t] = beg + excl;
        rs[b * 256 + t] = rsqrtf((float)(v + 1));
        cur[t] = beg + excl;
    }
    __syncthreads();
    for (int i = beg + t; i < end; i += 256) {
        unsigned p = ebuf[i];
        int pos = atomicAdd(&cur[p & 255], 1);
        col[pos] = (int)(p >> 8);
    }
}

// Swizzle for bf16-pair (uint) x-tile: row = 64 uints, XOR in 4-uint groups.
#define SWZU1(n, k2) ((n) * 64 + ((k2) ^ ((((n) & 7)) << 2)))

// ---- tiled GEMM1 (x-tile in bf16): xsb[n][c] = bf16(((x@W1+b1)[c])*rs[n]) ----
__global__ __launch_bounds__(256, 3) void k_gemm1(
    const float* __restrict__ x, const float* __restrict__ W1,
    const float* __restrict__ b1, const float* __restrict__ rs,
    ushort_t* __restrict__ xsb) {
    __shared__ unsigned xtb[64 * 64];  // 16 KB: 64 nodes x 64 bf16-pairs
    __shared__ float w1s[128 * 64];    // 32 KB
    int t = threadIdx.x;
    int base = blockIdx.x * 64;

#pragma unroll
    for (int i = 0; i < 8; ++i) {
        int flat = i * 1024 + t * 4;
        int node = flat >> 7, k0 = flat & 127;
        int gn = base + node;
        float4 v = make_float4(0.f, 0.f, 0.f, 0.f);
        if (gn < NN) v = *(const float4*)(x + (size_t)gn * IN_CH + k0);
        uint2 pk;
        pk.x = (unsigned)f2bf(v.x) | ((unsigned)f2bf(v.y) << 16);
        pk.y = (unsigned)f2bf(v.z) | ((unsigned)f2bf(v.w) << 16);
        *(uint2*)&xtb[SWZU1(node, k0 >> 1)] = pk;
        *(float4*)&w1s[flat] = *(const float4*)(W1 + flat);
    }
    __syncthreads();

    int tn = t & 15, tc = t >> 4;
    int c0 = tc * 4;
    float acc[4][4];
#pragma unroll
    for (int a = 0; a < 4; ++a)
#pragma unroll
        for (int b = 0; b < 4; ++b) acc[a][b] = 0.f;

    for (int k0 = 0; k0 < 128; k0 += 4) {
        int k2 = k0 >> 1;
        float xq[4][4], wq[4][4];
#pragma unroll
        for (int j = 0; j < 4; ++j)
            *(float4*)&wq[j][0] = *(float4*)&w1s[(k0 + j) * 64 + c0];
#pragma unroll
        for (int jn = 0; jn < 4; ++jn) {
            uint2 xu = *(uint2*)&xtb[SWZU1(tn + jn * 16, k2)];
            xq[jn][0] = blo(xu.x); xq[jn][1] = bhi(xu.x);
            xq[jn][2] = blo(xu.y); xq[jn][3] = bhi(xu.y);
        }
#pragma unroll
        for (int jn = 0; jn < 4; ++jn)
#pragma unroll
            for (int j = 0; j < 4; ++j)
#pragma unroll
                for (int jc = 0; jc < 4; ++jc)
                    acc[jn][jc] = fmaf(xq[jn][j], wq[j][jc], acc[jn][jc]);
    }

    float4 bb = *(const float4*)&b1[c0];
#pragma unroll
    for (int jn = 0; jn < 4; ++jn) {
        int gn = base + tn + jn * 16;
        if (gn < NN) {
            float r = rs[gn];
            uint2 pk;
            pk.x = (unsigned)f2bf((acc[jn][0] + bb.x) * r) |
                   ((unsigned)f2bf((acc[jn][1] + bb.y) * r) << 16);
            pk.y = (unsigned)f2bf((acc[jn][2] + bb.z) * r) |
                   ((unsigned)f2bf((acc[jn][3] + bb.w) * r) << 16);
            *(uint2*)&xsb[(size_t)gn * HID_CH + c0] = pk;
        }
    }
}

// ---- FUSED agg1 + relu + GEMM2: ysb[n][:] = bf16((relu(rs*agg)@W2+b2)*rs) ----
// 512 threads = 8 waves = 8 nodes/block. Gather as R7 agg1 (4 groups x 16
// lanes, uint2 = 4 bf16 ch). After shfl-combine each lane holds h[4*(lane&15)
// ..+3]; GEMV vs LDS W2: lane (half,c) accumulates k-range half*32..+31.
__global__ __launch_bounds__(512) void k_agg1g2(
    const int* __restrict__ rowptr, const int* __restrict__ col,
    const ushort_t* __restrict__ xsb, const float* __restrict__ rs,
    const float* __restrict__ W2, const float* __restrict__ b2,
    ushort_t* __restrict__ ysb) {
    __shared__ float w2s[HID_CH * OUT_CH];  // 8 KB
    __shared__ float b2s[OUT_CH];
    int t = threadIdx.x;
    {
        int flat = t * 4;  // 512*4 = 2048 floats
        *(float4*)&w2s[flat] = *(const float4*)(W2 + flat);
        if (t < OUT_CH) b2s[t] = b2[t];
    }
    __syncthreads();

    int n = blockIdx.x * 8 + (t >> 6);
    if (n >= NN) return;
    int lane = t & 63;
    int g = lane >> 4;                        // group 0..3
    unsigned c0 = (unsigned)(lane & 15) * 4;  // h channels c0..c0+3
    int beg = rowptr[n], end = rowptr[n + 1];

    float a0 = 0.f, a1 = 0.f, a2 = 0.f, a3 = 0.f;
    if (g == 0) {  // self-loop
        uint2 sv = *(const uint2*)&xsb[(unsigned)n * 64u + c0];
        a0 = blo(sv.x); a1 = bhi(sv.x); a2 = blo(sv.y); a3 = bhi(sv.y);
    }

    int i = beg;
    for (; i + 16 <= end; i += 16) {  // 16 edges/iter (4 per group)
        int s0 = col[i + g];
        int s1 = col[i + 4 + g];
        int s2 = col[i + 8 + g];
        int s3 = col[i + 12 + g];
        uint2 v0 = *(const uint2*)&xsb[(unsigned)s0 * 64u + c0];
        uint2 v1 = *(const uint2*)&xsb[(unsigned)s1 * 64u + c0];
        uint2 v2 = *(const uint2*)&xsb[(unsigned)s2 * 64u + c0];
        uint2 v3 = *(const uint2*)&xsb[(unsigned)s3 * 64u + c0];
        a0 += blo(v0.x); a1 += bhi(v0.x); a2 += blo(v0.y); a3 += bhi(v0.y);
        a0 += blo(v1.x); a1 += bhi(v1.x); a2 += blo(v1.y); a3 += bhi(v1.y);
        a0 += blo(v2.x); a1 += bhi(v2.x); a2 += blo(v2.y); a3 += bhi(v2.y);
        a0 += blo(v3.x); a1 += bhi(v3.x); a2 += blo(v3.y); a3 += bhi(v3.y);
    }
    for (; i + 4 <= end; i += 4) {
        int s0 = col[i + g];
        uint2 v0 = *(const uint2*)&xsb[(unsigned)s0 * 64u + c0];
        a0 += blo(v0.x); a1 += bhi(v0.x); a2 += blo(v0.y); a3 += bhi(v0.y);
    }
    int r = end - i;  // 0..3
    if (g < r) {
        int s0 = col[i + g];
        uint2 v0 = *(const uint2*)&xsb[(unsigned)s0 * 64u + c0];
        a0 += blo(v0.x); a1 += bhi(v0.x); a2 += blo(v0.y); a3 += bhi(v0.y);
    }

    // combine 4 groups -> every lane holds full sums for its 4 channels
    a0 += __shfl_xor(a0, 16); a1 += __shfl_xor(a1, 16);
    a2 += __shfl_xor(a2, 16); a3 += __shfl_xor(a3, 16);
    a0 += __shfl_xor(a0, 32); a1 += __shfl_xor(a1, 32);
    a2 += __shfl_xor(a2, 32); a3 += __shfl_xor(a3, 32);

    float rn = rs[n];
    a0 = fmaxf(a0 * rn, 0.f);  // h[c0+0]
    a1 = fmaxf(a1 * rn, 0.f);
    a2 = fmaxf(a2 * rn, 0.f);
    a3 = fmaxf(a3 * rn, 0.f);

    // GEMV: lane (half = lane>>5, c = lane&31) sums k = half*32 .. half*32+31
    int half = lane >> 5;
    int c = lane & 31;
    float y = half ? 0.f : b2s[c];
#pragma unroll
    for (int kc = 0; kc < 8; ++kc) {
        int kk = half * 8 + kc;            // source lane kk holds h[4kk..4kk+3]
        float h0 = __shfl(a0, kk);
        float h1 = __shfl(a1, kk);
        float h2 = __shfl(a2, kk);
        float h3 = __shfl(a3, kk);
        y = fmaf(h0, w2s[(4 * kk + 0) * OUT_CH + c], y);
        y = fmaf(h1, w2s[(4 * kk + 1) * OUT_CH + c], y);
        y = fmaf(h2, w2s[(4 * kk + 2) * OUT_CH + c], y);
        y = fmaf(h3, w2s[(4 * kk + 3) * OUT_CH + c], y);
    }
    y += __shfl_xor(y, 32);
    y *= rn;

    float ynext = __shfl_down(y, 1);
    if (half == 0 && (lane & 1) == 0) {
        unsigned pk = (unsigned)f2bf(y) | ((unsigned)f2bf(ynext) << 16);
        *(unsigned*)&ysb[(unsigned)n * 32u + (unsigned)c] = pk;
    }
}

// ---- pull agg layer 2: wave=row, 8 lane-groups x 8 lanes ----
__global__ __launch_bounds__(256) void k_agg2(
    const int* __restrict__ rowptr, const int* __restrict__ col,
    const ushort_t* __restrict__ ysb, const float* __restrict__ rs,
    float* __restrict__ out) {
    int gid = blockIdx.x * blockDim.x + threadIdx.x;
    int n = gid >> 6;
    if (n >= NN) return;
    int lane = threadIdx.x & 63;
    int g = lane >> 3;          // group 0..7
    unsigned c0 = (unsigned)(lane & 7) * 4;  // channels c0..c0+3
    int beg = rowptr[n], end = rowptr[n + 1];

    float a0 = 0.f, a1 = 0.f, a2 = 0.f, a3 = 0.f;
    if (g == 0) {
        uint2 sv = *(const uint2*)&ysb[(unsigned)n * 32u + c0];
        a0 = blo(sv.x); a1 = bhi(sv.x); a2 = blo(sv.y); a3 = bhi(sv.y);
    }

    int i = beg;
    for (; i + 16 <= end; i += 16) {  // 16 edges per iter (2 per group)
        int s0 = col[i + g];
        int s1 = col[i + 8 + g];
        uint2 v0 = *(const uint2*)&ysb[(unsigned)s0 * 32u + c0];
        uint2 v1 = *(const uint2*)&ysb[(unsigned)s1 * 32u + c0];
        a0 += blo(v0.x); a1 += bhi(v0.x); a2 += blo(v0.y); a3 += bhi(v0.y);
        a0 += blo(v1.x); a1 += bhi(v1.x); a2 += blo(v1.y); a3 += bhi(v1.y);
    }
    if (i + 8 <= end) {
        int s0 = col[i + g];
        uint2 v0 = *(const uint2*)&ysb[(unsigned)s0 * 32u + c0];
        a0 += blo(v0.x); a1 += bhi(v0.x); a2 += blo(v0.y); a3 += bhi(v0.y);
        i += 8;
    }
    int r = end - i;  // 0..7
    if (g < r) {
        int s0 = col[i + g];
        uint2 v0 = *(const uint2*)&ysb[(unsigned)s0 * 32u + c0];
        a0 += blo(v0.x); a1 += bhi(v0.x); a2 += blo(v0.y); a3 += bhi(v0.y);
    }

    // combine the 8 groups (xor 8, 16, 32)
    a0 += __shfl_xor(a0, 8);  a1 += __shfl_xor(a1, 8);
    a2 += __shfl_xor(a2, 8);  a3 += __shfl_xor(a3, 8);
    a0 += __shfl_xor(a0, 16); a1 += __shfl_xor(a1, 16);
    a2 += __shfl_xor(a2, 16); a3 += __shfl_xor(a3, 16);
    a0 += __shfl_xor(a0, 32); a1 += __shfl_xor(a1, 32);
    a2 += __shfl_xor(a2, 32); a3 += __shfl_xor(a3, 32);

    if (g == 0) {
        float rn = rs[n];
        float4 o;
        o.x = a0 * rn; o.y = a1 * rn; o.z = a2 * rn; o.w = a3 * rn;
        *(float4*)&out[(size_t)n * OUT_CH + c0] = o;
    }
}

extern "C" void kernel_launch(void* const* d_in, const int* in_sizes, int n_in,
                              void* d_out, int out_size, void* d_ws, size_t ws_size,
                              hipStream_t stream) {
    const float* x  = (const float*)d_in[0];
    const int*   ei = (const int*)d_in[1];  // (2, E): row 0 = src, row 1 = dst
    const float* W1 = (const float*)d_in[2];
    const float* b1 = (const float*)d_in[3];
    const float* W2 = (const float*)d_in[4];
    const float* b2 = (const float*)d_in[5];
    const int* sa = ei;
    const int* da = ei + NE;

    char* ws = (char*)d_ws;
    size_t off = 0;
    auto alloc = [&](size_t bytes) {
        void* p = ws + off;
        off += (bytes + 255) & ~(size_t)255;
        return p;
    };
    int*      bcnt   = (int*)alloc((size_t)NBUCK * 4);
    int*      bbase  = (int*)alloc((size_t)(NBUCK + 1) * 4);
    int*      bcur   = (int*)alloc((size_t)NBUCK * 4);
    int*      rowptr = (int*)alloc((size_t)(NN + 1) * 4);
    float*    rs     = (float*)alloc((size_t)NN * 4);
    unsigned* ebuf   = (unsigned*)alloc((size_t)NE * 4);
    int*      col    = (int*)alloc((size_t)NE * 4);
    ushort_t* xsb    = (ushort_t*)alloc((size_t)NN * HID_CH * 2);  // 12.8 MB
    ushort_t* ysb    = (ushort_t*)alloc((size_t)NN * OUT_CH * 2);  // 6.4 MB
    float*    outp   = (float*)d_out;

    const int B = 256;
    const int NBLKA = (NE + CHUNKA - 1) / CHUNKA;  // 196
    hipMemsetAsync(bcnt, 0, (size_t)NBUCK * 4, stream);
    k_bhist<<<NBLKA, 256, 0, stream>>>(da, bcnt);
    k_bscan<<<1, 512, 0, stream>>>(bcnt, bbase, bcur, rowptr);
    k_bfill<<<NBLKA, 256, 0, stream>>>(sa, da, bcur, ebuf);
    k_bfine<<<NBUCK, 256, 0, stream>>>(ebuf, bbase, rowptr, rs, col);

    const int NBLK_GEMM = (NN + 63) / 64;  // 1563
    k_gemm1<<<NBLK_GEMM, 256, 0, stream>>>(x, W1, b1, rs, xsb);
    k_agg1g2<<<(NN + 7) / 8, 512, 0, stream>>>(rowptr, col, xsb, rs, W2, b2, ysb);
    k_agg2<<<(NN * 64 + B - 1) / B, B, 0, stream>>>(rowptr, col, ysb, rs, outp);
}